// Round 6
// baseline (306.224 us; speedup 1.0000x reference)
//
#include <hip/hip_runtime.h>

#define KNN 16
#define FSEM 32

__device__ __forceinline__ float sigmoidf_(float x) { return 1.0f / (1.0f + __expf(-x)); }

// q / clip(|q|,1e-12) -> row-major 3x3
__device__ __forceinline__ void quat_to_R(float qw, float qx, float qy, float qz, float* R) {
    float d = qw * qw + qx * qx + qy * qy + qz * qz;
    float inv = rsqrtf(fmaxf(d, 1e-24f));
    float w = qw * inv, x = qx * inv, y = qy * inv, z = qz * inv;
    R[0] = 1.f - 2.f * (y * y + z * z); R[1] = 2.f * (x * y - w * z); R[2] = 2.f * (x * z + w * y);
    R[3] = 2.f * (x * y + w * z); R[4] = 1.f - 2.f * (x * x + z * z); R[5] = 2.f * (y * z - w * x);
    R[6] = 2.f * (x * z - w * y); R[7] = 2.f * (y * z + w * x); R[8] = 1.f - 2.f * (x * x + y * y);
}

__global__ void __launch_bounds__(256)
dynscf_kernel(const float* __restrict__ gs_xyz,
              const float* __restrict__ gs_rot,
              const float* __restrict__ gs_scal,
              const float* __restrict__ gs_opa,
              const float* __restrict__ feat_dc,
              const float* __restrict__ feat_rest,
              const float* __restrict__ node_xyz,
              const float* __restrict__ node_quat,
              const float* __restrict__ node_sigma,
              const float* __restrict__ node_sem,
              const int* __restrict__ attach_ind,
              const int* __restrict__ ref_time,
              const int* __restrict__ topo_knn,
              const int* __restrict__ t_ptr,
              float* __restrict__ out,
              int N, int M)
{
    const int n = blockIdx.x * blockDim.x + threadIdx.x;
    if (n >= N) return;

    const int t  = t_ptr[0];
    const int a  = attach_ind[n];
    const int rt = ref_time[n];

    const size_t base_rt = (size_t)rt * (size_t)M;
    const size_t base_t  = (size_t)t  * (size_t)M;

    // --- attach node at ref time ---
    const float4 qa = *reinterpret_cast<const float4*>(node_quat + (base_rt + (size_t)a) * 4);
    float Rref[9];
    quat_to_R(qa.x, qa.y, qa.z, qa.w, Rref);

    const float* pa = node_xyz + (base_rt + (size_t)a) * 3;
    const float px = pa[0], py = pa[1], pz = pa[2];

    const float gx = gs_xyz[3 * (size_t)n + 0];
    const float gy = gs_xyz[3 * (size_t)n + 1];
    const float gz = gs_xyz[3 * (size_t)n + 2];

    const float xw0 = Rref[0] * gx + Rref[1] * gy + Rref[2] * gz + px;
    const float xw1 = Rref[3] * gx + Rref[4] * gy + Rref[5] * gz + py;
    const float xw2 = Rref[6] * gx + Rref[7] * gy + Rref[8] * gz + pz;

    // R_world = R_ref @ q2R(gs_rotation)
    const float4 qg = *reinterpret_cast<const float4*>(gs_rot + 4 * (size_t)n);
    float Rg[9];
    quat_to_R(qg.x, qg.y, qg.z, qg.w, Rg);
    float Rw[9];
#pragma unroll
    for (int i = 0; i < 3; i++)
#pragma unroll
        for (int j = 0; j < 3; j++)
            Rw[3 * i + j] = Rref[3 * i] * Rg[j] + Rref[3 * i + 1] * Rg[3 + j] + Rref[3 * i + 2] * Rg[6 + j];

    // --- K-neighbor skinning loop ---
    float wsum = 0.f, mu0 = 0.f, mu1 = 0.f, mu2 = 0.f;
    float qb0 = 0.f, qb1 = 0.f, qb2 = 0.f, qb3 = 0.f;
    float sem[FSEM];
#pragma unroll
    for (int f = 0; f < FSEM; f++) sem[f] = 0.f;

    const int* knn = topo_knn + (size_t)a * KNN;

    for (int k = 0; k < KNN; k++) {
        const int j = knn[k];

        const float* pr = node_xyz + (base_rt + (size_t)j) * 3;
        const float dx = xw0 - pr[0];
        const float dy = xw1 - pr[1];
        const float dz = xw2 - pr[2];
        const float dsq = dx * dx + dy * dy + dz * dz;

        const float sg = node_sigma[j];
        const float w = __expf(-dsq / (2.f * sg * sg + 1e-8f));

        // q_ref / q_live normalized
        const float4 qrv = *reinterpret_cast<const float4*>(node_quat + (base_rt + (size_t)j) * 4);
        float rw = qrv.x, rx = qrv.y, ry = qrv.z, rz = qrv.w;
        {
            float inv = rsqrtf(fmaxf(rw * rw + rx * rx + ry * ry + rz * rz, 1e-24f));
            rw *= inv; rx *= inv; ry *= inv; rz *= inv;
        }
        const float4 qlv = *reinterpret_cast<const float4*>(node_quat + (base_t + (size_t)j) * 4);
        float lw = qlv.x, lx = qlv.y, ly = qlv.z, lz = qlv.w;
        {
            float inv = rsqrtf(fmaxf(lw * lw + lx * lx + ly * ly + lz * lz, 1e-24f));
            lw *= inv; lx *= inv; ly *= inv; lz *= inv;
        }
        // q_rel = q_live * conj(q_ref)
        const float qw =  lw * rw + lx * rx + ly * ry + lz * rz;
        const float qx = -lw * rx + lx * rw - ly * rz + lz * ry;
        const float qy = -lw * ry + lx * rz + ly * rw - lz * rx;
        const float qz = -lw * rz - lx * ry + ly * rx + lz * rw;

        float Rr[9];
        quat_to_R(qw, qx, qy, qz, Rr);

        const float* pl = node_xyz + (base_t + (size_t)j) * 3;
        const float m0 = Rr[0] * dx + Rr[1] * dy + Rr[2] * dz + pl[0];
        const float m1 = Rr[3] * dx + Rr[4] * dy + Rr[5] * dz + pl[1];
        const float m2 = Rr[6] * dx + Rr[7] * dy + Rr[8] * dz + pl[2];

        wsum += w;
        mu0 += w * m0; mu1 += w * m1; mu2 += w * m2;
        qb0 += w * qw; qb1 += w * qx; qb2 += w * qy; qb3 += w * qz;

        const float4* sp4 = reinterpret_cast<const float4*>(node_sem + (size_t)j * FSEM);
#pragma unroll
        for (int q = 0; q < 8; q++) {
            float4 v = sp4[q];
            sem[q * 4 + 0] += w * v.x;
            sem[q * 4 + 1] += w * v.y;
            sem[q * 4 + 2] += w * v.z;
            sem[q * 4 + 3] += w * v.w;
        }
    }

    const float invw = 1.f / (wsum + 1e-8f);

    // fr_live = q2R(q_blend) @ R_world.
    // CRITICAL: scale qb by invw BEFORE q2R — reproduces the reference's
    // normalized-weight blend. Unnormalized qb can sit at ~1e-20 (all weights
    // underflow-ish), where |qb|^2 denormalizes in fp32 and q2R collapses to I
    // while the fp64 numpy ref still produces a genuine rotation. (r5 bug: 1.875)
    float Rb[9];
    quat_to_R(qb0 * invw, qb1 * invw, qb2 * invw, qb3 * invw, Rb);
    float Fr[9];
#pragma unroll
    for (int i = 0; i < 3; i++)
#pragma unroll
        for (int j = 0; j < 3; j++)
            Fr[3 * i + j] = Rb[3 * i] * Rw[j] + Rb[3 * i + 1] * Rw[3 + j] + Rb[3 * i + 2] * Rw[6 + j];

    const size_t Ns = (size_t)N, ns = (size_t)n;

    // mu_live: [0, 3N)
    out[3 * ns + 0] = mu0 * invw;
    out[3 * ns + 1] = mu1 * invw;
    out[3 * ns + 2] = mu2 * invw;

    // fr_live: [3N, 12N)
    float* ofr = out + 3 * Ns + 9 * ns;
#pragma unroll
    for (int i = 0; i < 9; i++) ofr[i] = Fr[i];

    // s: [12N, 15N)
    float* os = out + 12 * Ns + 3 * ns;
#pragma unroll
    for (int c = 0; c < 3; c++)
        os[c] = 0.1f * sigmoidf_(gs_scal[3 * ns + c]);

    // o: [15N, 16N)
    out[15 * Ns + ns] = sigmoidf_(gs_opa[ns]);

    // sph: [16N, 28N) = concat(feat_dc, feat_rest); offsets 16N+12n are 16B-aligned
    float* osph = out + 16 * Ns + 12 * ns;
    {
        float4 v0 = make_float4(feat_dc[3 * ns + 0], feat_dc[3 * ns + 1], feat_dc[3 * ns + 2],
                                feat_rest[9 * ns + 0]);
        float4 v1 = make_float4(feat_rest[9 * ns + 1], feat_rest[9 * ns + 2],
                                feat_rest[9 * ns + 3], feat_rest[9 * ns + 4]);
        float4 v2 = make_float4(feat_rest[9 * ns + 5], feat_rest[9 * ns + 6],
                                feat_rest[9 * ns + 7], feat_rest[9 * ns + 8]);
        reinterpret_cast<float4*>(osph)[0] = v0;
        reinterpret_cast<float4*>(osph)[1] = v1;
        reinterpret_cast<float4*>(osph)[2] = v2;
    }

    // sem_live: [28N, 60N); offsets 28N+32n are 16B-aligned
    float4* osem = reinterpret_cast<float4*>(out + 28 * Ns + FSEM * ns);
#pragma unroll
    for (int q = 0; q < 8; q++)
        osem[q] = make_float4(sem[4 * q + 0] * invw, sem[4 * q + 1] * invw,
                              sem[4 * q + 2] * invw, sem[4 * q + 3] * invw);
}

extern "C" void kernel_launch(void* const* d_in, const int* in_sizes, int n_in,
                              void* d_out, int out_size, void* d_ws, size_t ws_size,
                              hipStream_t stream)
{
    const float* gs_xyz     = (const float*)d_in[0];
    const float* gs_rot     = (const float*)d_in[1];
    const float* gs_scal    = (const float*)d_in[2];
    const float* gs_opa     = (const float*)d_in[3];
    const float* feat_dc    = (const float*)d_in[4];
    const float* feat_rest  = (const float*)d_in[5];
    const float* node_xyz   = (const float*)d_in[6];
    const float* node_quat  = (const float*)d_in[7];
    const float* node_sigma = (const float*)d_in[8];
    const float* node_sem   = (const float*)d_in[9];
    const int* attach_ind   = (const int*)d_in[10];
    const int* ref_time     = (const int*)d_in[11];
    const int* topo_knn     = (const int*)d_in[12];
    const int* t_ptr        = (const int*)d_in[13];

    const int N = in_sizes[0] / 3;
    const int M = in_sizes[8];          // node_sigma is (M,1)

    float* out = (float*)d_out;

    const int block = 256;
    const int grid = (N + block - 1) / block;
    hipLaunchKernelGGL(dynscf_kernel, dim3(grid), dim3(block), 0, stream,
                       gs_xyz, gs_rot, gs_scal, gs_opa, feat_dc, feat_rest,
                       node_xyz, node_quat, node_sigma, node_sem,
                       attach_ind, ref_time, topo_knn, t_ptr, out, N, M);
}